// Round 1
// 614.079 us; speedup vs baseline: 1.0768x; 1.0768x over previous
//
#include <hip/hip_runtime.h>

// TransformerDecoderLayerQaN — MI355X round 7.
// R7: attn_wp rewritten — cooperative (block-shared) K/V staging instead of
// 4x redundant wave-private copies; K staged via global_load_lds in fragment
// order (conflict-free b128 frag reads, zero VALU); V staged via cooperative
// register transpose with 2-way-free bank mapping; double-buffered LDS with
// prefetch (issue chunk c+1 loads before computing chunk c). LDS 44KB -> 23KB
// (3 -> 6 blocks/CU). Everything else identical to R6.
//
// ws layout (total 61,689,856 B — same envelope as R2/R4/R5):
//   qeff  f32 [10*512]   @ 0
//   p     f32 [B*NQ*T]   @ 20480
//   Acomb f32 [B*NW*48]  @ 675840
//   mixed f32 [B*NW*D]   @ 872448
//   y1    bf16 [T*B*D]   @ 2969600    (reused: fb = lin2 out)
//   qb    bf16 [T*B*D]   @ 19746816   (reused: t1 = out_proj out; hb = FFN hidden 4096x2048)
//   kvb   bf16 [S*B][1024] @ 36524032 (K cols 0..511, V cols 512..1023)
//     post-attn reuse: opwb @36524032 (512KB), l1wb @37048320 (2MB), l2wb @39145472 (2MB)
//   ob    bf16 [T*B*D]   @ 44912640   (reused: y2 = LN2 out)
//     pre-attn reuse: ipwb bf16[1536*512] @44912640, memb bf16[4096*512] @46485504

typedef unsigned short u16;
typedef unsigned int u32;
typedef short short8_t __attribute__((ext_vector_type(8)));
typedef float f32x4 __attribute__((ext_vector_type(4)));

#define TT 2048
#define BB 8
#define SS 512
#define DD 512
#define HH 8
#define DH 64
#define DFF 2048
#define NQ 10
#define WW 16
#define NW 128
#define KVS 1024   // fused KV row stride (elements)

__device__ __forceinline__ float b2f(u16 u) {
    return __uint_as_float(((unsigned int)u) << 16);
}
__device__ __forceinline__ u16 f2b(float f) {
    unsigned int x = __float_as_uint(f);
    unsigned int r = x + 0x7FFFu + ((x >> 16) & 1u);
    return (u16)(r >> 16);
}
__device__ __forceinline__ float wave_sum(float v) {
    #pragma unroll
    for (int o = 32; o > 0; o >>= 1) v += __shfl_xor(v, o, 64);
    return v;
}
__device__ __forceinline__ float wave_max(float v) {
    #pragma unroll
    for (int o = 32; o > 0; o >>= 1) v = fmaxf(v, __shfl_xor(v, o, 64));
    return v;
}
__device__ __forceinline__ void load4(const u16* p, float* v) {
    ushort4 t = *(const ushort4*)p;
    v[0] = b2f(t.x); v[1] = b2f(t.y); v[2] = b2f(t.z); v[3] = b2f(t.w);
}
__device__ __forceinline__ void load4(const float* p, float* v) {
    float4 t = *(const float4*)p;
    v[0] = t.x; v[1] = t.y; v[2] = t.z; v[3] = t.w;
}
__device__ __forceinline__ void st1(u16* p, float v) { *p = f2b(v); }
__device__ __forceinline__ void st1(float* p, float v) { *p = v; }

// async global->LDS, 16B per lane; lds dest = wave-uniform base + lane*16
__device__ __forceinline__ void async16(const u16* g, u16* l) {
    __builtin_amdgcn_global_load_lds((const __attribute__((address_space(1))) u32*)g,
                                     (__attribute__((address_space(3))) u32*)l, 16, 0, 0);
}

// ---------------- f32 -> bf16 convert ----------------
__global__ __launch_bounds__(256) void cvt_kernel(const float* __restrict__ src,
                                                  u16* __restrict__ dst) {
    int i = (blockIdx.x * 256 + threadIdx.x) * 4;
    float4 v = *(const float4*)(src + i);
    ushort4 o;
    o.x = f2b(v.x); o.y = f2b(v.y); o.z = f2b(v.z); o.w = f2b(v.w);
    *(ushort4*)(dst + i) = o;
}

// ---------------- QA block (R2 verbatim) ----------------
__global__ __launch_bounds__(512) void qeff_kernel(const float* __restrict__ queries,
                                                   float* __restrict__ qeff) {
    int d = threadIdx.x;
    const float KS = 0.0055242717280199026f; // 1/(8*sqrt(512))
    for (int n = 0; n < NQ; n++) {
        float v = queries[n * DD + d];
        float ss = wave_sum(v * v);
        float norm = sqrtf(ss);
        qeff[n * DD + d] = v / (norm + 1e-6f) * KS;
    }
}

__global__ __launch_bounds__(256) void p_kernel(const float* __restrict__ x,
                                                const float* __restrict__ qeff,
                                                float* __restrict__ p) {
    __shared__ float qe[NQ * DD];
    for (int i = threadIdx.x; i < NQ * DD; i += 256) qe[i] = qeff[i];
    __syncthreads();
    int b = blockIdx.x >> 9;
    int t = ((blockIdx.x & 511) << 2) + (threadIdx.x >> 6);
    int lane = threadIdx.x & 63;
    const float* xr = x + ((size_t)t * BB + b) * DD;
    float acc[NQ];
    #pragma unroll
    for (int n = 0; n < NQ; n++) acc[n] = 0.f;
    #pragma unroll
    for (int c = 0; c < 8; c++) {
        int d = c * 64 + lane;
        float xv = xr[d];
        #pragma unroll
        for (int n = 0; n < NQ; n++) acc[n] += xv * qe[n * DD + d];
    }
    #pragma unroll
    for (int n = 0; n < NQ; n++) {
        float s = wave_sum(acc[n]);
        if (lane == 0) p[((size_t)(b * NQ + n)) * TT + t] = s;
    }
}

__global__ __launch_bounds__(256) void win_kernel(const float* __restrict__ p,
                                                  const float* __restrict__ wk,
                                                  float* __restrict__ Acomb) {
    int id = blockIdx.x * 4 + (threadIdx.x >> 6); // b*NW + m
    int b = id >> 7, m = id & 127;
    int j = threadIdx.x & 63;
    int tj = (m - 1) * WW + j;
    bool valid = (j < 48) && (tj >= 0) && (tj < TT);
    float acc = 0.f;
    for (int n = 0; n < NQ; n++) {
        float v = valid ? p[((size_t)(b * NQ + n)) * TT + tj] : -1e30f;
        float mx = wave_max(v);
        float e = valid ? __expf(v - mx) : 0.f;
        float s = wave_sum(e);
        acc += wk[n] * (e / s);
    }
    if (j < 48) Acomb[(size_t)id * 48 + j] = acc;
}

__global__ __launch_bounds__(256) void mix_kernel(const float* __restrict__ Acomb,
                                                  const float* __restrict__ x,
                                                  float* __restrict__ mixed) {
    __shared__ float As[48];
    int id = blockIdx.x;
    int b = id >> 7, m = id & 127;
    if (threadIdx.x < 48) As[threadIdx.x] = Acomb[(size_t)id * 48 + threadIdx.x];
    __syncthreads();
    int d0 = threadIdx.x, d1 = threadIdx.x + 256;
    float a0 = 0.f, a1 = 0.f;
    int tb = (m - 1) * WW;
    for (int j = 0; j < 48; j++) {
        int t = tb + j;
        if ((unsigned)t < (unsigned)TT) {
            float aj = As[j];
            const float* xr = x + ((size_t)t * BB + b) * DD;
            a0 += aj * xr[d0];
            a1 += aj * xr[d1];
        }
    }
    mixed[(size_t)id * DD + d0] = a0;
    mixed[(size_t)id * DD + d1] = a1;
}

__global__ __launch_bounds__(256) void ln_qa_kernel(const float* __restrict__ a,
                                                    const float* __restrict__ mixed,
                                                    const float* __restrict__ g,
                                                    const float* __restrict__ bt,
                                                    u16* __restrict__ out) {
    int r = blockIdx.x * 4 + (threadIdx.x >> 6); // r = t*B+b
    int lane = threadIdx.x & 63;
    int t = r >> 3, b = r & 7;
    const float* ar = a + (size_t)r * DD;
    const float* mr = mixed + ((size_t)(b * NW + (t >> 4))) * DD;
    int d0 = lane * 8;
    float av[8], mv[8], gg[8], bb[8];
    load4(ar + d0, av); load4(ar + d0 + 4, av + 4);
    load4(mr + d0, mv); load4(mr + d0 + 4, mv + 4);
    load4(g + d0, gg);  load4(g + d0 + 4, gg + 4);
    load4(bt + d0, bb); load4(bt + d0 + 4, bb + 4);
    float v[8];
    float s = 0.f, s2 = 0.f;
    #pragma unroll
    for (int u = 0; u < 8; u++) { v[u] = av[u] + mv[u]; s += v[u]; s2 += v[u] * v[u]; }
    s = wave_sum(s); s2 = wave_sum(s2);
    float mu = s * (1.f / DD);
    float var = s2 * (1.f / DD) - mu * mu;
    float rs = rsqrtf(var + 1e-5f);
    #pragma unroll
    for (int u = 0; u < 8; u++) out[(size_t)r * DD + d0 + u] = f2b((v[u] - mu) * rs * gg[u] + bb[u]);
}

template <typename OT>
__global__ __launch_bounds__(256) void ln_rows_kernel(const u16* __restrict__ a,
                                                      const u16* __restrict__ bsrc,
                                                      const float* __restrict__ g,
                                                      const float* __restrict__ bt,
                                                      OT* __restrict__ out) {
    int r = blockIdx.x * 4 + (threadIdx.x >> 6);
    int lane = threadIdx.x & 63;
    const u16* ar = a + (size_t)r * DD;
    const u16* br = bsrc + (size_t)r * DD;
    int d0 = lane * 8;
    float av[8], cv[8], gg[8], bb[8];
    load4(ar + d0, av); load4(ar + d0 + 4, av + 4);
    load4(br + d0, cv); load4(br + d0 + 4, cv + 4);
    load4(g + d0, gg);  load4(g + d0 + 4, gg + 4);
    load4(bt + d0, bb); load4(bt + d0 + 4, bb + 4);
    float v[8];
    float s = 0.f, s2 = 0.f;
    #pragma unroll
    for (int u = 0; u < 8; u++) { v[u] = av[u] + cv[u]; s += v[u]; s2 += v[u] * v[u]; }
    s = wave_sum(s); s2 = wave_sum(s2);
    float mu = s * (1.f / DD);
    float var = s2 * (1.f / DD) - mu * mu;
    float rs = rsqrtf(var + 1e-5f);
    #pragma unroll
    for (int u = 0; u < 8; u++) st1(out + (size_t)r * DD + d0 + u, (v[u] - mu) * rs * gg[u] + bb[u]);
}

// ---------------- MFMA GEMM with global_load_lds staging ----------------
// C[M,N] = act(A[M,K] @ W[N,K]^T + bias). A,W bf16; C bf16; bias f32.
// BM = MT*32 (MT=4 -> 128, MT=2 -> 64), BN=128, BK=32. 4 waves (2x2).
template <int RELU, int MT>
__global__ __launch_bounds__(256) void gemm_lds(const u16* __restrict__ A,
                                                const u16* __restrict__ W,
                                                const float* __restrict__ bias,
                                                u16* __restrict__ C,
                                                int M, int N, int K) {
    constexpr int BM = MT * 32;
    constexpr int NIA = BM / 64;   // A DMA insts per wave
    __shared__ u16 As[BM * 32];
    __shared__ u16 Bs[128 * 32];
    int tid = threadIdx.x;
    int w = tid >> 6, lane = tid & 63;
    int n16 = lane & 15, quad = lane >> 4;
    int m0 = blockIdx.y * BM, n0 = blockIdx.x * 128;
    int wm16 = (w >> 1) * MT;       // m-block base (16-row units) for frags
    int wn = (w & 1) * 64;

    const u16* gA[NIA];
    u16* lA[NIA];
    #pragma unroll
    for (int i = 0; i < NIA; i++) {
        int s = (w * NIA + i) * 64 + lane;
        int mb = s >> 6, kseg = (s >> 4) & 3, m = s & 15;
        gA[i] = A + (size_t)(m0 + mb * 16 + m) * K + kseg * 8;
        lA[i] = As + (size_t)((w * NIA + i) * 64) * 8;
    }
    const u16* gB[2];
    u16* lB[2];
    #pragma unroll
    for (int i = 0; i < 2; i++) {
        int s = (w * 2 + i) * 64 + lane;
        int nb = s >> 6, kseg = (s >> 4) & 3, n = s & 15;
        gB[i] = W + (size_t)(n0 + nb * 16 + n) * K + kseg * 8;
        lB[i] = Bs + (size_t)((w * 2 + i) * 64) * 8;
    }

    f32x4 acc[MT][4];
    #pragma unroll
    for (int i = 0; i < MT; i++)
        #pragma unroll
        for (int j = 0; j < 4; j++) acc[i][j] = (f32x4){0.f, 0.f, 0.f, 0.f};

    for (int k0 = 0; k0 < K; k0 += 32) {
        __syncthreads();               // previous tile fully consumed
        #pragma unroll
        for (int i = 0; i < NIA; i++) async16(gA[i] + k0, lA[i]);
        #pragma unroll
        for (int i = 0; i < 2; i++) async16(gB[i] + k0, lB[i]);
        __syncthreads();               // DMA drained (vmcnt0 at barrier)
        short8_t af[MT], bf[4];
        #pragma unroll
        for (int im = 0; im < MT; im++)
            af[im] = *(const short8_t*)(As + (size_t)((wm16 + im) * 64 + lane) * 8);
        #pragma unroll
        for (int in = 0; in < 4; in++)
            bf[in] = *(const short8_t*)(Bs + (size_t)(((w & 1) * 4 + in) * 64 + lane) * 8);
        #pragma unroll
        for (int im = 0; im < MT; im++)
            #pragma unroll
            for (int in = 0; in < 4; in++)
                acc[im][in] = __builtin_amdgcn_mfma_f32_16x16x32_bf16(af[im], bf[in], acc[im][in], 0, 0, 0);
    }

    float bia[4];
    #pragma unroll
    for (int in = 0; in < 4; in++) bia[in] = bias[n0 + wn + in * 16 + n16];
    #pragma unroll
    for (int im = 0; im < MT; im++) {
        #pragma unroll
        for (int r = 0; r < 4; r++) {
            int row = m0 + (wm16 + im) * 16 + quad * 4 + r;
            u16* crow = C + (size_t)row * N + n0 + wn + n16;
            #pragma unroll
            for (int in = 0; in < 4; in++) {
                float v = acc[im][in][r] + bia[in];
                if (RELU) v = fmaxf(v, 0.f);
                crow[in * 16] = f2b(v);
            }
        }
    }
}

// ---------------- MFMA flash attention, cooperative double-buffered ----------------
// grid (T/64, B*H), 4 waves; wave w owns 16 q-rows. K/V staged ONCE per block
// (shared across waves), double-buffered:
//   K: global_load_lds in fragment order (frag f = nt*2+kh at Kb[buf][f*512+lane*8]),
//      1 DMA inst per wave per chunk, conflict-free b128 frag reads.
//   V: cooperative register transpose. Wave w covers d-range [w*16, w*16+16):
//      lane: keys {2kp, 2kp+1} (kp = lane&15), d = w*16 + quad*4 .. +4.
//      u32 writes -> banks ((lane>>4)*16 + (lane&15)) % 32: 2-way (free).
// Prefetch: chunk c+1's V global loads + K DMA issue BEFORE chunk c's compute;
// V LDS write after compute; __syncthreads() (implicit vmcnt(0)+lgkmcnt(0)
// drain) closes the chunk -> DMA/HBM latency hides under MFMA+softmax.
// Fixed softmax max M=8 (scores O(1)); l per-lane, reduced once at the end.
__global__ __launch_bounds__(256) void attn_wp(const u16* __restrict__ qb,
                                               const u16* __restrict__ kvb,
                                               u16* __restrict__ ob) {
    __shared__ u16 Kb[2][2048];        // fragment order, 4KB per buffer
    __shared__ u16 Vt[2][64][40];      // V^T [d][key], stride 40 (2-way free)
    __shared__ u16 Ps[4][16][40];      // per-wave P round-trip
    int tid = threadIdx.x;
    int w = tid >> 6, lane = tid & 63;
    int n16 = lane & 15, quad = lane >> 4, q8 = quad * 8;
    int b = blockIdx.y >> 3, h = blockIdx.y & 7;
    int q0 = blockIdx.x * 64 + w * 16;
    const int RS = BB * KVS;           // kvb row stride (elements)

    const u16* qrow = qb + ((size_t)(q0 + n16) * BB + b) * DD + h * DH;
    short8_t aq0 = *(const short8_t*)(qrow + q8);
    short8_t aq1 = *(const short8_t*)(qrow + 32 + q8);

    const u16* kbase = kvb + (size_t)b * KVS + h * DH;
    const u16* vbase = kvb + 512 + (size_t)b * KVS + h * DH;

    // K DMA: wave w stages frag f=w (nt = w>>1, kh = w&1).
    // lane source: K[row = nt*16 + n16][d = kh*32 + quad*8 .. +8] (16B contig).
    const u16* gK = kbase + (size_t)((w >> 1) * 16 + n16) * RS + (w & 1) * 32 + q8;
    // V source: lane reads keys {kp2, kp2+1} x d [vd, vd+4) (8B each).
    int kp2 = (lane & 15) * 2;
    int vd = w * 16 + quad * 4;
    const u16* gV = vbase + (size_t)kp2 * RS + vd;

    float lsum[4];
    f32x4 Oa[4];
    #pragma unroll
    for (int r = 0; r < 4; r++) lsum[r] = 0.f;
    #pragma unroll
    for (int ot = 0; ot < 4; ot++) Oa[ot] = (f32x4){0.f, 0.f, 0.f, 0.f};

    union VU { ushort4 q; u16 h[4]; };

    // ---- stage chunk 0 ----
    {
        async16(gK, &Kb[0][w * 512]);
        VU va, vb2;
        va.q  = *(const ushort4*)(gV);
        vb2.q = *(const ushort4*)(gV + RS);
        #pragma unroll
        for (int u = 0; u < 4; u++)
            *(u32*)&Vt[0][vd + u][kp2] = (u32)va.h[u] | ((u32)vb2.h[u] << 16);
    }
    __syncthreads();

    for (int c = 0; c < 16; c++) {
        int cur = c & 1, nxt = cur ^ 1;

        // ---- prefetch chunk c+1 (issue loads; consume after compute) ----
        VU va, vb2;
        if (c < 15) {
            const u16* gVc = gV + (size_t)(c + 1) * 32 * RS;
            va.q  = *(const ushort4*)(gVc);
            vb2.q = *(const ushort4*)(gVc + RS);
            async16(gK + (size_t)(c + 1) * 32 * RS, &Kb[nxt][w * 512]);
        }

        // ---- scores S[16 q][32 keys] from Kb[cur] ----
        f32x4 sc[2];
        #pragma unroll
        for (int nt = 0; nt < 2; nt++) {
            short8_t bk0 = *(const short8_t*)&Kb[cur][(nt * 2 + 0) * 512 + lane * 8];
            short8_t bk1 = *(const short8_t*)&Kb[cur][(nt * 2 + 1) * 512 + lane * 8];
            f32x4 a = (f32x4){0.f, 0.f, 0.f, 0.f};
            a = __builtin_amdgcn_mfma_f32_16x16x32_bf16(aq0, bk0, a, 0, 0, 0);
            a = __builtin_amdgcn_mfma_f32_16x16x32_bf16(aq1, bk1, a, 0, 0, 0);
            sc[nt] = a;
        }

        // ---- fixed-max softmax: p = exp(s/8 - 8); per-lane l accumulation ----
        #pragma unroll
        for (int r = 0; r < 4; r++) {
            float p0 = __expf(sc[0][r] * 0.125f - 8.0f);
            float p1 = __expf(sc[1][r] * 0.125f - 8.0f);
            lsum[r] += p0 + p1;
            Ps[w][quad * 4 + r][n16] = f2b(p0);
            Ps[w][quad * 4 + r][16 + n16] = f2b(p1);
        }

        // ---- O += P @ V from Vt[cur] ----
        short8_t ap = *(const short8_t*)&Ps[w][n16][q8];
        #pragma unroll
        for (int ot = 0; ot < 4; ot++) {
            short8_t bv = *(const short8_t*)&Vt[cur][ot * 16 + n16][q8];
            Oa[ot] = __builtin_amdgcn_mfma_f32_16x16x32_bf16(ap, bv, Oa[ot], 0, 0, 0);
        }

        // ---- write prefetched V into Vt[nxt] ----
        if (c < 15) {
            #pragma unroll
            for (int u = 0; u < 4; u++)
                *(u32*)&Vt[nxt][vd + u][kp2] = (u32)va.h[u] | ((u32)vb2.h[u] << 16);
        }
        __syncthreads();   // drains my K-DMA (vmcnt0) + orders LDS across waves
    }

    #pragma unroll
    for (int r = 0; r < 4; r++) {
        float l = lsum[r];
        #pragma unroll
        for (int o = 1; o < 16; o <<= 1) l += __shfl_xor(l, o, 64);
        float inv = 1.f / l;
        int t = q0 + quad * 4 + r;
        u16* orow = ob + ((size_t)t * BB + b) * DD + h * DH + n16;
        #pragma unroll
        for (int ot = 0; ot < 4; ot++) orow[ot * 16] = f2b(Oa[ot][r] * inv);
    }
}

// ---------------- host ----------------
extern "C" void kernel_launch(void* const* d_in, const int* in_sizes, int n_in,
                              void* d_out, int out_size, void* d_ws, size_t ws_size,
                              hipStream_t stream) {
    const float* tgt       = (const float*)d_in[0];
    const float* memory    = (const float*)d_in[1];
    const float* queries   = (const float*)d_in[2];
    const float* wk        = (const float*)d_in[3];
    const float* in_proj_w = (const float*)d_in[4];
    const float* in_proj_b = (const float*)d_in[5];
    const float* out_proj_w= (const float*)d_in[6];
    const float* out_proj_b= (const float*)d_in[7];
    const float* lin1_w    = (const float*)d_in[8];
    const float* lin1_b    = (const float*)d_in[9];
    const float* lin2_w    = (const float*)d_in[10];
    const float* lin2_b    = (const float*)d_in[11];
    const float* ln1_g     = (const float*)d_in[12];
    const float* ln1_b     = (const float*)d_in[13];
    const float* ln2_g     = (const float*)d_in[14];
    const float* ln2_b     = (const float*)d_in[15];
    const float* ln3_g     = (const float*)d_in[16];
    const float* ln3_b     = (const float*)d_in[17];

    char* w = (char*)d_ws;
    float* qeff  = (float*)(w + 0);
    float* pbuf  = (float*)(w + 20480);
    float* Acomb = (float*)(w + 675840);
    float* mixed = (float*)(w + 872448);
    u16* y1  = (u16*)(w + 2969600);
    u16* qb  = (u16*)(w + 19746816);
    u16* kvb = (u16*)(w + 36524032);   // 8.4MB fused KV
    u16* ob  = (u16*)(w + 44912640);
    // pre-attention residents of the ob region (dead before attn writes ob):
    u16* ipwb = (u16*)(w + 44912640);  // in_proj_w bf16 [1536*512]
    u16* memb = (u16*)(w + 46485504);  // memory bf16 [4096*512]
    // post-attention residents of the kvb region (kvb dead after attn):
    u16* opwb = (u16*)(w + 36524032);  // out_proj_w bf16 [512*512]
    u16* l1wb = (u16*)(w + 37048320);  // lin1_w bf16 [2048*512]
    u16* l2wb = (u16*)(w + 39145472);  // lin2_w bf16 [512*2048]
    u16* t1 = qb;  // out_proj result (qb dead after attention)
    u16* y2 = ob;  // LN2 out (ob = attn out, dead after out_proj)
    u16* hb = qb;  // FFN hidden chunk 4096x2048 (qb/t1 dead after LN2)
    u16* fb = y1;  // lin2 out (y1 dead after LN2)

    // ---- pre-attention weight/input conversion (into ob region) ----
    cvt_kernel<<<(SS * BB * DD) / 1024, 256, 0, stream>>>(memory, memb);
    cvt_kernel<<<(3 * DD * DD) / 1024, 256, 0, stream>>>(in_proj_w, ipwb);

    // ---- QA block ----
    qeff_kernel<<<1, 512, 0, stream>>>(queries, qeff);
    p_kernel<<<BB * (TT / 4), 256, 0, stream>>>(tgt, qeff, pbuf);
    win_kernel<<<(BB * NW) / 4, 256, 0, stream>>>(pbuf, wk, Acomb);
    mix_kernel<<<BB * NW, 256, 0, stream>>>(Acomb, tgt, mixed);
    ln_qa_kernel<<<(TT * BB) / 4, 256, 0, stream>>>(tgt, mixed, ln1_g, ln1_b, y1);

    // ---- MHA ----
    gemm_lds<0, 4><<<dim3(DD / 128, (TT * BB) / 128), 256, 0, stream>>>(y1, ipwb, in_proj_b, qb, TT * BB, DD, DD);
    gemm_lds<0, 4><<<dim3(KVS / 128, (SS * BB) / 128), 256, 0, stream>>>(memb, ipwb + (size_t)DD * DD, in_proj_b + DD, kvb, SS * BB, KVS, DD);
    attn_wp<<<dim3(TT / 64, BB * HH), 256, 0, stream>>>(qb, kvb, ob);
    // kvb dead; convert remaining weights into its region
    cvt_kernel<<<(DD * DD) / 1024, 256, 0, stream>>>(out_proj_w, opwb);
    cvt_kernel<<<(DFF * DD) / 1024, 256, 0, stream>>>(lin1_w, l1wb);
    cvt_kernel<<<(DD * DFF) / 1024, 256, 0, stream>>>(lin2_w, l2wb);
    gemm_lds<0, 4><<<dim3(DD / 128, (TT * BB) / 128), 256, 0, stream>>>(ob, opwb, out_proj_b, t1, TT * BB, DD, DD);
    ln_rows_kernel<u16><<<(TT * BB) / 4, 256, 0, stream>>>(y1, t1, ln2_g, ln2_b, y2);

    // ---- FFN (4 chunks of 4096 rows; hidden in qb region) ----
    for (int c = 0; c < 4; c++) {
        const u16* y2c = y2 + (size_t)c * 4096 * DD;
        u16* fbc = fb + (size_t)c * 4096 * DD;
        gemm_lds<1, 4><<<dim3(DFF / 128, 4096 / 128), 256, 0, stream>>>(y2c, l1wb, lin1_b, hb, 4096, DFF, DD);
        gemm_lds<0, 2><<<dim3(DD / 128, 4096 / 64), 256, 0, stream>>>(hb, l2wb, lin2_b, fbc, 4096, DD, DFF);
    }
    ln_rows_kernel<float><<<(TT * BB) / 4, 256, 0, stream>>>(y2, fb, ln3_g, ln3_b, (float*)d_out);
}

// Round 2
// 565.739 us; speedup vs baseline: 1.1688x; 1.0854x over previous
//
#include <hip/hip_runtime.h>

// TransformerDecoderLayerQaN — MI355X round 8.
// R8: (1) KV stored head-major [part][b][h][s][64] by a templated gemm_lds
// epilogue -> attn K/V staging reads contiguous 4KB chunks (key stride 128B,
// was 16KB): full-line coalescing, no gather serialization, less over-fetch.
// (2) gemm_lds double-buffered: issue next tile's global_load_lds BEFORE
// computing current tile; single barrier per K-step (implicit vmcnt(0) drain
// lands after the MFMAs) -> staging latency hidden under compute on all 12
// GEMM dispatches. attn schedule itself unchanged from R7.
//
// ws layout (total 61,689,856 B — same envelope):
//   qeff  f32 [10*512]   @ 0
//   p     f32 [B*NQ*T]   @ 20480
//   Acomb f32 [B*NW*48]  @ 675840
//   mixed f32 [B*NW*D]   @ 872448
//   y1    bf16 [T*B*D]   @ 2969600    (reused: fb = lin2 out)
//   qb    bf16 [T*B*D]   @ 19746816   (reused: t1 = out_proj out; hb = FFN hidden)
//   kvb   bf16 [2][B][H][S][64] @ 36524032  (K part 0, V part 1; 8.4MB)
//     post-attn reuse: opwb @36524032, l1wb @37048320, l2wb @39145472
//   ob    bf16 [T*B*D]   @ 44912640   (reused: y2 = LN2 out)
//     pre-attn reuse: ipwb bf16[1536*512] @44912640, memb bf16[4096*512] @46485504

typedef unsigned short u16;
typedef unsigned int u32;
typedef short short8_t __attribute__((ext_vector_type(8)));
typedef float f32x4 __attribute__((ext_vector_type(4)));

#define TT 2048
#define BB 8
#define SS 512
#define DD 512
#define HH 8
#define DH 64
#define DFF 2048
#define NQ 10
#define WW 16
#define NW 128
#define KVPART 2097152   // elems per K / V part: B*H*S*DH = 8*8*512*64

__device__ __forceinline__ float b2f(u16 u) {
    return __uint_as_float(((unsigned int)u) << 16);
}
__device__ __forceinline__ u16 f2b(float f) {
    unsigned int x = __float_as_uint(f);
    unsigned int r = x + 0x7FFFu + ((x >> 16) & 1u);
    return (u16)(r >> 16);
}
__device__ __forceinline__ float wave_sum(float v) {
    #pragma unroll
    for (int o = 32; o > 0; o >>= 1) v += __shfl_xor(v, o, 64);
    return v;
}
__device__ __forceinline__ float wave_max(float v) {
    #pragma unroll
    for (int o = 32; o > 0; o >>= 1) v = fmaxf(v, __shfl_xor(v, o, 64));
    return v;
}
__device__ __forceinline__ void load4(const u16* p, float* v) {
    ushort4 t = *(const ushort4*)p;
    v[0] = b2f(t.x); v[1] = b2f(t.y); v[2] = b2f(t.z); v[3] = b2f(t.w);
}
__device__ __forceinline__ void load4(const float* p, float* v) {
    float4 t = *(const float4*)p;
    v[0] = t.x; v[1] = t.y; v[2] = t.z; v[3] = t.w;
}
__device__ __forceinline__ void st1(u16* p, float v) { *p = f2b(v); }
__device__ __forceinline__ void st1(float* p, float v) { *p = v; }

// async global->LDS, 16B per lane; lds dest = wave-uniform base + lane*16
__device__ __forceinline__ void async16(const u16* g, u16* l) {
    __builtin_amdgcn_global_load_lds((const __attribute__((address_space(1))) u32*)g,
                                     (__attribute__((address_space(3))) u32*)l, 16, 0, 0);
}

// ---------------- f32 -> bf16 convert ----------------
__global__ __launch_bounds__(256) void cvt_kernel(const float* __restrict__ src,
                                                  u16* __restrict__ dst) {
    int i = (blockIdx.x * 256 + threadIdx.x) * 4;
    float4 v = *(const float4*)(src + i);
    ushort4 o;
    o.x = f2b(v.x); o.y = f2b(v.y); o.z = f2b(v.z); o.w = f2b(v.w);
    *(ushort4*)(dst + i) = o;
}

// ---------------- QA block (R2 verbatim) ----------------
__global__ __launch_bounds__(512) void qeff_kernel(const float* __restrict__ queries,
                                                   float* __restrict__ qeff) {
    int d = threadIdx.x;
    const float KS = 0.0055242717280199026f; // 1/(8*sqrt(512))
    for (int n = 0; n < NQ; n++) {
        float v = queries[n * DD + d];
        float ss = wave_sum(v * v);
        float norm = sqrtf(ss);
        qeff[n * DD + d] = v / (norm + 1e-6f) * KS;
    }
}

__global__ __launch_bounds__(256) void p_kernel(const float* __restrict__ x,
                                                const float* __restrict__ qeff,
                                                float* __restrict__ p) {
    __shared__ float qe[NQ * DD];
    for (int i = threadIdx.x; i < NQ * DD; i += 256) qe[i] = qeff[i];
    __syncthreads();
    int b = blockIdx.x >> 9;
    int t = ((blockIdx.x & 511) << 2) + (threadIdx.x >> 6);
    int lane = threadIdx.x & 63;
    const float* xr = x + ((size_t)t * BB + b) * DD;
    float acc[NQ];
    #pragma unroll
    for (int n = 0; n < NQ; n++) acc[n] = 0.f;
    #pragma unroll
    for (int c = 0; c < 8; c++) {
        int d = c * 64 + lane;
        float xv = xr[d];
        #pragma unroll
        for (int n = 0; n < NQ; n++) acc[n] += xv * qe[n * DD + d];
    }
    #pragma unroll
    for (int n = 0; n < NQ; n++) {
        float s = wave_sum(acc[n]);
        if (lane == 0) p[((size_t)(b * NQ + n)) * TT + t] = s;
    }
}

__global__ __launch_bounds__(256) void win_kernel(const float* __restrict__ p,
                                                  const float* __restrict__ wk,
                                                  float* __restrict__ Acomb) {
    int id = blockIdx.x * 4 + (threadIdx.x >> 6); // b*NW + m
    int b = id >> 7, m = id & 127;
    int j = threadIdx.x & 63;
    int tj = (m - 1) * WW + j;
    bool valid = (j < 48) && (tj >= 0) && (tj < TT);
    float acc = 0.f;
    for (int n = 0; n < NQ; n++) {
        float v = valid ? p[((size_t)(b * NQ + n)) * TT + tj] : -1e30f;
        float mx = wave_max(v);
        float e = valid ? __expf(v - mx) : 0.f;
        float s = wave_sum(e);
        acc += wk[n] * (e / s);
    }
    if (j < 48) Acomb[(size_t)id * 48 + j] = acc;
}

__global__ __launch_bounds__(256) void mix_kernel(const float* __restrict__ Acomb,
                                                  const float* __restrict__ x,
                                                  float* __restrict__ mixed) {
    __shared__ float As[48];
    int id = blockIdx.x;
    int b = id >> 7, m = id & 127;
    if (threadIdx.x < 48) As[threadIdx.x] = Acomb[(size_t)id * 48 + threadIdx.x];
    __syncthreads();
    int d0 = threadIdx.x, d1 = threadIdx.x + 256;
    float a0 = 0.f, a1 = 0.f;
    int tb = (m - 1) * WW;
    for (int j = 0; j < 48; j++) {
        int t = tb + j;
        if ((unsigned)t < (unsigned)TT) {
            float aj = As[j];
            const float* xr = x + ((size_t)t * BB + b) * DD;
            a0 += aj * xr[d0];
            a1 += aj * xr[d1];
        }
    }
    mixed[(size_t)id * DD + d0] = a0;
    mixed[(size_t)id * DD + d1] = a1;
}

__global__ __launch_bounds__(256) void ln_qa_kernel(const float* __restrict__ a,
                                                    const float* __restrict__ mixed,
                                                    const float* __restrict__ g,
                                                    const float* __restrict__ bt,
                                                    u16* __restrict__ out) {
    int r = blockIdx.x * 4 + (threadIdx.x >> 6); // r = t*B+b
    int lane = threadIdx.x & 63;
    int t = r >> 3, b = r & 7;
    const float* ar = a + (size_t)r * DD;
    const float* mr = mixed + ((size_t)(b * NW + (t >> 4))) * DD;
    int d0 = lane * 8;
    float av[8], mv[8], gg[8], bb[8];
    load4(ar + d0, av); load4(ar + d0 + 4, av + 4);
    load4(mr + d0, mv); load4(mr + d0 + 4, mv + 4);
    load4(g + d0, gg);  load4(g + d0 + 4, gg + 4);
    load4(bt + d0, bb); load4(bt + d0 + 4, bb + 4);
    float v[8];
    float s = 0.f, s2 = 0.f;
    #pragma unroll
    for (int u = 0; u < 8; u++) { v[u] = av[u] + mv[u]; s += v[u]; s2 += v[u] * v[u]; }
    s = wave_sum(s); s2 = wave_sum(s2);
    float mu = s * (1.f / DD);
    float var = s2 * (1.f / DD) - mu * mu;
    float rs = rsqrtf(var + 1e-5f);
    #pragma unroll
    for (int u = 0; u < 8; u++) out[(size_t)r * DD + d0 + u] = f2b((v[u] - mu) * rs * gg[u] + bb[u]);
}

template <typename OT>
__global__ __launch_bounds__(256) void ln_rows_kernel(const u16* __restrict__ a,
                                                      const u16* __restrict__ bsrc,
                                                      const float* __restrict__ g,
                                                      const float* __restrict__ bt,
                                                      OT* __restrict__ out) {
    int r = blockIdx.x * 4 + (threadIdx.x >> 6);
    int lane = threadIdx.x & 63;
    const u16* ar = a + (size_t)r * DD;
    const u16* br = bsrc + (size_t)r * DD;
    int d0 = lane * 8;
    float av[8], cv[8], gg[8], bb[8];
    load4(ar + d0, av); load4(ar + d0 + 4, av + 4);
    load4(br + d0, cv); load4(br + d0 + 4, cv + 4);
    load4(g + d0, gg);  load4(g + d0 + 4, gg + 4);
    load4(bt + d0, bb); load4(bt + d0 + 4, bb + 4);
    float v[8];
    float s = 0.f, s2 = 0.f;
    #pragma unroll
    for (int u = 0; u < 8; u++) { v[u] = av[u] + cv[u]; s += v[u]; s2 += v[u] * v[u]; }
    s = wave_sum(s); s2 = wave_sum(s2);
    float mu = s * (1.f / DD);
    float var = s2 * (1.f / DD) - mu * mu;
    float rs = rsqrtf(var + 1e-5f);
    #pragma unroll
    for (int u = 0; u < 8; u++) st1(out + (size_t)r * DD + d0 + u, (v[u] - mu) * rs * gg[u] + bb[u]);
}

// ---------------- MFMA GEMM, double-buffered global_load_lds staging ----------------
// C = act(A[M,K] @ W[N,K]^T + bias). BM = MT*32, BN=128, BK=32, 4 waves (2x2).
// Per K-step: issue next tile's DMA into buf^1, compute buf, ONE barrier
// (implicit vmcnt(0)+lgkmcnt(0) drain sits after the MFMAs -> latency hidden).
// KV=1: store C head-major kvb[part][b][h][s][64] (part=col>>9, h=(col>>6)&7).
template <int RELU, int MT, int KV>
__global__ __launch_bounds__(256) void gemm_lds(const u16* __restrict__ A,
                                                const u16* __restrict__ W,
                                                const float* __restrict__ bias,
                                                u16* __restrict__ C,
                                                int M, int N, int K) {
    constexpr int BM = MT * 32;
    constexpr int NIA = BM / 64;   // A DMA insts per wave
    __shared__ u16 As[2][BM * 32];
    __shared__ u16 Bs[2][128 * 32];
    int tid = threadIdx.x;
    int w = tid >> 6, lane = tid & 63;
    int n16 = lane & 15, quad = lane >> 4;
    int m0 = blockIdx.y * BM, n0 = blockIdx.x * 128;
    int wm16 = (w >> 1) * MT;       // m-block base (16-row units) for frags
    int wn = (w & 1) * 64;

    const u16* gA[NIA];
    u16* lA[NIA];
    #pragma unroll
    for (int i = 0; i < NIA; i++) {
        int s = (w * NIA + i) * 64 + lane;
        int mb = s >> 6, kseg = (s >> 4) & 3, m = s & 15;
        gA[i] = A + (size_t)(m0 + mb * 16 + m) * K + kseg * 8;
        lA[i] = &As[0][(size_t)((w * NIA + i) * 64) * 8];
    }
    const u16* gB[2];
    u16* lB[2];
    #pragma unroll
    for (int i = 0; i < 2; i++) {
        int s = (w * 2 + i) * 64 + lane;
        int nb = s >> 6, kseg = (s >> 4) & 3, n = s & 15;
        gB[i] = W + (size_t)(n0 + nb * 16 + n) * K + kseg * 8;
        lB[i] = &Bs[0][(size_t)((w * 2 + i) * 64) * 8];
    }

    f32x4 acc[MT][4];
    #pragma unroll
    for (int i = 0; i < MT; i++)
        #pragma unroll
        for (int j = 0; j < 4; j++) acc[i][j] = (f32x4){0.f, 0.f, 0.f, 0.f};

    const int nk = K >> 5;
    // prologue: stage tile 0 into buffer 0
    #pragma unroll
    for (int i = 0; i < NIA; i++) async16(gA[i], lA[i]);
    #pragma unroll
    for (int i = 0; i < 2; i++) async16(gB[i], lB[i]);
    __syncthreads();

    for (int t = 0; t < nk; t++) {
        int cur = t & 1;
        if (t + 1 < nk) {
            int nxt = cur ^ 1;
            #pragma unroll
            for (int i = 0; i < NIA; i++) async16(gA[i] + (t + 1) * 32, lA[i] + nxt * (BM * 32));
            #pragma unroll
            for (int i = 0; i < 2; i++) async16(gB[i] + (t + 1) * 32, lB[i] + nxt * 4096);
        }
        const u16* Ac = &As[cur][0];
        const u16* Bc = &Bs[cur][0];
        short8_t af[MT], bf[4];
        #pragma unroll
        for (int im = 0; im < MT; im++)
            af[im] = *(const short8_t*)(Ac + (size_t)((wm16 + im) * 64 + lane) * 8);
        #pragma unroll
        for (int in = 0; in < 4; in++)
            bf[in] = *(const short8_t*)(Bc + (size_t)(((w & 1) * 4 + in) * 64 + lane) * 8);
        #pragma unroll
        for (int im = 0; im < MT; im++)
            #pragma unroll
            for (int in = 0; in < 4; in++)
                acc[im][in] = __builtin_amdgcn_mfma_f32_16x16x32_bf16(af[im], bf[in], acc[im][in], 0, 0, 0);
        __syncthreads();   // drains next-tile DMA; all waves done reading cur
    }

    float bia[4];
    #pragma unroll
    for (int in = 0; in < 4; in++) bia[in] = bias[n0 + wn + in * 16 + n16];
    #pragma unroll
    for (int im = 0; im < MT; im++) {
        #pragma unroll
        for (int r = 0; r < 4; r++) {
            int row = m0 + (wm16 + im) * 16 + quad * 4 + r;
            #pragma unroll
            for (int in = 0; in < 4; in++) {
                float v = acc[im][in][r] + bia[in];
                if (RELU) v = fmaxf(v, 0.f);
                if (KV) {
                    int col = n0 + wn + in * 16 + n16;
                    int part = col >> 9, h = (col >> 6) & 7, d = col & 63;
                    int s = row >> 3, bq = row & 7;
                    C[(size_t)part * KVPART + ((size_t)(bq * HH + h) * SS + s) * DH + d] = f2b(v);
                } else {
                    C[(size_t)row * N + n0 + wn + in * 16 + n16] = f2b(v);
                }
            }
        }
    }
}

// ---------------- MFMA flash attention, cooperative double-buffered ----------------
// grid (T/64, B*H), 4 waves; wave w owns 16 q-rows. K/V staged ONCE per block
// from head-major kvb[part][b][h][s][64] — a 32-key chunk is 4KB CONTIGUOUS.
//   K: global_load_lds in fragment order (frag f=w at Kb[buf][w*512+lane*8]),
//      conflict-free b128 frag reads; source lines fully used.
//   V: cooperative register transpose (wave w covers d-range [w*16,w*16+16));
//      u32 writes 2-way bank-free; source rows 128B apart (2 lines / instr).
// Prefetch: chunk c+1's V loads + K DMA issue BEFORE chunk c's compute; V LDS
// write after compute; per-chunk __syncthreads (vmcnt0 drain) closes the chunk.
// Fixed softmax max M=8; l per-lane, reduced once at the end.
__global__ __launch_bounds__(256) void attn_wp(const u16* __restrict__ qb,
                                               const u16* __restrict__ kvb,
                                               u16* __restrict__ ob) {
    __shared__ u16 Kb[2][2048];        // fragment order, 4KB per buffer
    __shared__ u16 Vt[2][64][40];      // V^T [d][key], stride 40 (2-way free)
    __shared__ u16 Ps[4][16][40];      // per-wave P round-trip
    int tid = threadIdx.x;
    int w = tid >> 6, lane = tid & 63;
    int n16 = lane & 15, quad = lane >> 4, q8 = quad * 8;
    int b = blockIdx.y >> 3, h = blockIdx.y & 7;
    int q0 = blockIdx.x * 64 + w * 16;

    const u16* qrow = qb + ((size_t)(q0 + n16) * BB + b) * DD + h * DH;
    short8_t aq0 = *(const short8_t*)(qrow + q8);
    short8_t aq1 = *(const short8_t*)(qrow + 32 + q8);

    const u16* kbase = kvb + (size_t)(b * HH + h) * (SS * DH);
    const u16* vbase = kvb + (size_t)KVPART + (size_t)(b * HH + h) * (SS * DH);

    // K DMA: wave w stages frag f=w (nt = w>>1, kh = w&1).
    // lane source: K[key = nt*16 + n16][d = kh*32 + quad*8 .. +8] (16B contig).
    const u16* gK = kbase + (size_t)((w >> 1) * 16 + n16) * DH + (w & 1) * 32 + q8;
    // V source: lane reads keys {kp2, kp2+1} x d [vd, vd+4) (8B each).
    int kp2 = (lane & 15) * 2;
    int vd = w * 16 + quad * 4;
    const u16* gV = vbase + (size_t)kp2 * DH + vd;

    float lsum[4];
    f32x4 Oa[4];
    #pragma unroll
    for (int r = 0; r < 4; r++) lsum[r] = 0.f;
    #pragma unroll
    for (int ot = 0; ot < 4; ot++) Oa[ot] = (f32x4){0.f, 0.f, 0.f, 0.f};

    union VU { ushort4 q; u16 h[4]; };

    // ---- stage chunk 0 ----
    {
        async16(gK, &Kb[0][w * 512]);
        VU va, vb2;
        va.q  = *(const ushort4*)(gV);
        vb2.q = *(const ushort4*)(gV + DH);
        #pragma unroll
        for (int u = 0; u < 4; u++)
            *(u32*)&Vt[0][vd + u][kp2] = (u32)va.h[u] | ((u32)vb2.h[u] << 16);
    }
    __syncthreads();

    for (int c = 0; c < 16; c++) {
        int cur = c & 1, nxt = cur ^ 1;

        // ---- prefetch chunk c+1 (issue loads; consume after compute) ----
        VU va, vb2;
        if (c < 15) {
            const u16* gVc = gV + (size_t)(c + 1) * 32 * DH;
            va.q  = *(const ushort4*)(gVc);
            vb2.q = *(const ushort4*)(gVc + DH);
            async16(gK + (size_t)(c + 1) * 32 * DH, &Kb[nxt][w * 512]);
        }

        // ---- scores S[16 q][32 keys] from Kb[cur] ----
        f32x4 sc[2];
        #pragma unroll
        for (int nt = 0; nt < 2; nt++) {
            short8_t bk0 = *(const short8_t*)&Kb[cur][(nt * 2 + 0) * 512 + lane * 8];
            short8_t bk1 = *(const short8_t*)&Kb[cur][(nt * 2 + 1) * 512 + lane * 8];
            f32x4 a = (f32x4){0.f, 0.f, 0.f, 0.f};
            a = __builtin_amdgcn_mfma_f32_16x16x32_bf16(aq0, bk0, a, 0, 0, 0);
            a = __builtin_amdgcn_mfma_f32_16x16x32_bf16(aq1, bk1, a, 0, 0, 0);
            sc[nt] = a;
        }

        // ---- fixed-max softmax: p = exp(s/8 - 8); per-lane l accumulation ----
        #pragma unroll
        for (int r = 0; r < 4; r++) {
            float p0 = __expf(sc[0][r] * 0.125f - 8.0f);
            float p1 = __expf(sc[1][r] * 0.125f - 8.0f);
            lsum[r] += p0 + p1;
            Ps[w][quad * 4 + r][n16] = f2b(p0);
            Ps[w][quad * 4 + r][16 + n16] = f2b(p1);
        }

        // ---- O += P @ V from Vt[cur] ----
        short8_t ap = *(const short8_t*)&Ps[w][n16][q8];
        #pragma unroll
        for (int ot = 0; ot < 4; ot++) {
            short8_t bv = *(const short8_t*)&Vt[cur][ot * 16 + n16][q8];
            Oa[ot] = __builtin_amdgcn_mfma_f32_16x16x32_bf16(ap, bv, Oa[ot], 0, 0, 0);
        }

        // ---- write prefetched V into Vt[nxt] ----
        if (c < 15) {
            #pragma unroll
            for (int u = 0; u < 4; u++)
                *(u32*)&Vt[nxt][vd + u][kp2] = (u32)va.h[u] | ((u32)vb2.h[u] << 16);
        }
        __syncthreads();   // drains my K-DMA (vmcnt0) + orders LDS across waves
    }

    #pragma unroll
    for (int r = 0; r < 4; r++) {
        float l = lsum[r];
        #pragma unroll
        for (int o = 1; o < 16; o <<= 1) l += __shfl_xor(l, o, 64);
        float inv = 1.f / l;
        int t = q0 + quad * 4 + r;
        u16* orow = ob + ((size_t)t * BB + b) * DD + h * DH + n16;
        #pragma unroll
        for (int ot = 0; ot < 4; ot++) orow[ot * 16] = f2b(Oa[ot][r] * inv);
    }
}

// ---------------- host ----------------
extern "C" void kernel_launch(void* const* d_in, const int* in_sizes, int n_in,
                              void* d_out, int out_size, void* d_ws, size_t ws_size,
                              hipStream_t stream) {
    const float* tgt       = (const float*)d_in[0];
    const float* memory    = (const float*)d_in[1];
    const float* queries   = (const float*)d_in[2];
    const float* wk        = (const float*)d_in[3];
    const float* in_proj_w = (const float*)d_in[4];
    const float* in_proj_b = (const float*)d_in[5];
    const float* out_proj_w= (const float*)d_in[6];
    const float* out_proj_b= (const float*)d_in[7];
    const float* lin1_w    = (const float*)d_in[8];
    const float* lin1_b    = (const float*)d_in[9];
    const float* lin2_w    = (const float*)d_in[10];
    const float* lin2_b    = (const float*)d_in[11];
    const float* ln1_g     = (const float*)d_in[12];
    const float* ln1_b     = (const float*)d_in[13];
    const float* ln2_g     = (const float*)d_in[14];
    const float* ln2_b     = (const float*)d_in[15];
    const float* ln3_g     = (const float*)d_in[16];
    const float* ln3_b     = (const float*)d_in[17];

    char* w = (char*)d_ws;
    float* qeff  = (float*)(w + 0);
    float* pbuf  = (float*)(w + 20480);
    float* Acomb = (float*)(w + 675840);
    float* mixed = (float*)(w + 872448);
    u16* y1  = (u16*)(w + 2969600);
    u16* qb  = (u16*)(w + 19746816);
    u16* kvb = (u16*)(w + 36524032);   // 8.4MB head-major KV
    u16* ob  = (u16*)(w + 44912640);
    // pre-attention residents of the ob region (dead before attn writes ob):
    u16* ipwb = (u16*)(w + 44912640);  // in_proj_w bf16 [1536*512]
    u16* memb = (u16*)(w + 46485504);  // memory bf16 [4096*512]
    // post-attention residents of the kvb region (kvb dead after attn):
    u16* opwb = (u16*)(w + 36524032);  // out_proj_w bf16 [512*512]
    u16* l1wb = (u16*)(w + 37048320);  // lin1_w bf16 [2048*512]
    u16* l2wb = (u16*)(w + 39145472);  // lin2_w bf16 [512*2048]
    u16* t1 = qb;  // out_proj result (qb dead after attention)
    u16* y2 = ob;  // LN2 out (ob = attn out, dead after out_proj)
    u16* hb = qb;  // FFN hidden chunk 4096x2048 (qb/t1 dead after LN2)
    u16* fb = y1;  // lin2 out (y1 dead after LN2)

    // ---- pre-attention weight/input conversion (into ob region) ----
    cvt_kernel<<<(SS * BB * DD) / 1024, 256, 0, stream>>>(memory, memb);
    cvt_kernel<<<(3 * DD * DD) / 1024, 256, 0, stream>>>(in_proj_w, ipwb);

    // ---- QA block ----
    qeff_kernel<<<1, 512, 0, stream>>>(queries, qeff);
    p_kernel<<<BB * (TT / 4), 256, 0, stream>>>(tgt, qeff, pbuf);
    win_kernel<<<(BB * NW) / 4, 256, 0, stream>>>(pbuf, wk, Acomb);
    mix_kernel<<<BB * NW, 256, 0, stream>>>(Acomb, tgt, mixed);
    ln_qa_kernel<<<(TT * BB) / 4, 256, 0, stream>>>(tgt, mixed, ln1_g, ln1_b, y1);

    // ---- MHA ----
    gemm_lds<0, 4, 0><<<dim3(DD / 128, (TT * BB) / 128), 256, 0, stream>>>(y1, ipwb, in_proj_b, qb, TT * BB, DD, DD);
    gemm_lds<0, 4, 1><<<dim3(1024 / 128, (SS * BB) / 128), 256, 0, stream>>>(memb, ipwb + (size_t)DD * DD, in_proj_b + DD, kvb, SS * BB, 1024, DD);
    attn_wp<<<dim3(TT / 64, BB * HH), 256, 0, stream>>>(qb, kvb, ob);
    // kvb dead; convert remaining weights into its region
    cvt_kernel<<<(DD * DD) / 1024, 256, 0, stream>>>(out_proj_w, opwb);
    cvt_kernel<<<(DFF * DD) / 1024, 256, 0, stream>>>(lin1_w, l1wb);
    cvt_kernel<<<(DD * DFF) / 1024, 256, 0, stream>>>(lin2_w, l2wb);
    gemm_lds<0, 4, 0><<<dim3(DD / 128, (TT * BB) / 128), 256, 0, stream>>>(ob, opwb, out_proj_b, t1, TT * BB, DD, DD);
    ln_rows_kernel<u16><<<(TT * BB) / 4, 256, 0, stream>>>(y1, t1, ln2_g, ln2_b, y2);

    // ---- FFN (4 chunks of 4096 rows; hidden in qb region) ----
    for (int c = 0; c < 4; c++) {
        const u16* y2c = y2 + (size_t)c * 4096 * DD;
        u16* fbc = fb + (size_t)c * 4096 * DD;
        gemm_lds<1, 4, 0><<<dim3(DFF / 128, 4096 / 128), 256, 0, stream>>>(y2c, l1wb, lin1_b, hb, 4096, DFF, DD);
        gemm_lds<0, 2, 0><<<dim3(DD / 128, 4096 / 64), 256, 0, stream>>>(hb, l2wb, lin2_b, fbc, 4096, DD, DFF);
    }
    ln_rows_kernel<float><<<(TT * BB) / 4, 256, 0, stream>>>(y2, fb, ln3_g, ln3_b, (float*)d_out);
}